// Round 1
// baseline (340.225 us; speedup 1.0000x reference)
//
#include <hip/hip_runtime.h>
#include <hip/hip_bf16.h>

#define CC 128   // channels
#define HH 128   // hidden

typedef __attribute__((ext_vector_type(8))) short frag_ab;
typedef __attribute__((ext_vector_type(4))) float f32x4;

__device__ __forceinline__ unsigned short f2bf(float f) {
    union { float f; unsigned int u; } v; v.f = f;
    unsigned int u = v.u;
    u += 0x7FFFu + ((u >> 16) & 1u);   // round-to-nearest-even
    return (unsigned short)(u >> 16);
}

// One persistent block = 512 threads = 8 waves. Each wave owns a 16-column
// tile of W2 (B-fragments in registers, loaded once). Per node:
//   phase 1: 512 threads compute h = gelu(agg@W1+b1) (16 edges x 128 hidden),
//            fp32 math, bf16 into XOR-swizzled LDS tile (4 KB).
//   phase 2: each wave does 4x mfma_f32_16x16x32_bf16 -> 16x16 msg tile,
//            then gathers in_features, weighted-accumulates, shfl-reduces
//            over edges, stores segment mean.
__global__ __launch_bounds__(512, 4)
void nmlp_kernel(const float* __restrict__ x_in,
                 const float* __restrict__ x_out,
                 const float* __restrict__ in_feat,
                 const int* __restrict__ nbr,
                 const int* __restrict__ row_splits,
                 const float* __restrict__ W1,
                 const float* __restrict__ b1,
                 const float* __restrict__ W2,
                 const float* __restrict__ b2,
                 float* __restrict__ out,
                 int N, int M)
{
    // h tile: 16 rows x 128 bf16 = 256 B/row; XOR-swizzle (row&7)<<4 on byte
    // offsets so ds_read_b128 of a column-strip is bank-conflict-free (G4).
    __shared__ __align__(16) char hb[16 * 256];

    const int tid  = threadIdx.x;
    const int lane = tid & 63;
    const int wave = tid >> 6;        // 0..7
    const int cbase = wave * 16;      // W2 column tile
    const int col  = lane & 15;
    const int kgrp = lane >> 4;       // 0..3

    // ---- hoisted per-thread constants (invariant across nodes) ----
    // phase-1 assignment: this thread computes h[he][hk0 .. hk0+3]
    const int v4  = tid * 4;
    const int he  = v4 >> 7;          // edge row 0..15
    const int hk0 = v4 & 127;         // hidden col base (multiple of 4)
    float w1v[24];
    float b1v[4];
    #pragma unroll
    for (int kk = 0; kk < 6; ++kk)
        #pragma unroll
        for (int j = 0; j < 4; ++j)
            w1v[kk*4+j] = W1[kk*HH + hk0 + j];
    #pragma unroll
    for (int j = 0; j < 4; ++j) b1v[j] = b1[hk0 + j];
    const int hwoff = he*256 + ((hk0*2) ^ ((he & 7) << 4));

    // B fragments: this wave's W2 column tile, bf16, registers (once/block)
    frag_ab bfrag[4];
    #pragma unroll
    for (int kb = 0; kb < 4; ++kb) {
        #pragma unroll
        for (int i = 0; i < 8; ++i) {
            int k = kb*32 + kgrp*8 + i;
            bfrag[kb][i] = (short)f2bf(W2[k*CC + cbase + col]);
        }
    }
    const float b2c = b2[cbase + col];
    const float* inf0 = in_feat;
    const float* inf1 = in_feat + (size_t)N * CC;

    const int rrow  = lane & 15;           // A-frag row
    const int abase = rrow * 256;
    const int akoff = kgrp * 16;           // byte offset of this lane's 8 bf16

    for (int m = blockIdx.x; m < M; m += gridDim.x) {
        const int start = row_splits[m];
        const int deg   = row_splits[m+1] - start;

        // ---- phase 1: h = gelu(agg @ W1 + b1) -> bf16 LDS ----
        {
            const bool valid = he < deg;
            const int id = valid ? nbr[start + he] : 0;
            float a0 = valid ? x_in[id*3+0] : 0.f;
            float a1 = valid ? x_in[id*3+1] : 0.f;
            float a2 = valid ? x_in[id*3+2] : 0.f;
            float a3 = valid ? x_out[m*3+0] : 0.f;
            float a4 = valid ? x_out[m*3+1] : 0.f;
            float a5 = valid ? x_out[m*3+2] : 0.f;
            unsigned short us[4];
            #pragma unroll
            for (int j = 0; j < 4; ++j) {
                float pre = b1v[j];
                pre += a0*w1v[0*4+j]; pre += a1*w1v[1*4+j];
                pre += a2*w1v[2*4+j]; pre += a3*w1v[3*4+j];
                pre += a4*w1v[4*4+j]; pre += a5*w1v[5*4+j];
                float g = 0.5f * pre * (1.f + erff(pre * 0.70710678118654752f));
                us[j] = f2bf(g);
            }
            unsigned int lo = (unsigned int)us[0] | ((unsigned int)us[1] << 16);
            unsigned int hi = (unsigned int)us[2] | ((unsigned int)us[3] << 16);
            *reinterpret_cast<uint2*>(hb + hwoff) = make_uint2(lo, hi);
        }
        __syncthreads();

        // ---- phase 2: msg = h @ W2 + b2 (MFMA), weighted gather, mean ----
        {
            f32x4 acc = {0.f, 0.f, 0.f, 0.f};
            #pragma unroll
            for (int kb = 0; kb < 4; ++kb) {
                int koff = kb*64 + akoff;
                frag_ab af = *reinterpret_cast<const frag_ab*>(
                    hb + abase + (koff ^ ((rrow & 7) << 4)));
                acc = __builtin_amdgcn_mfma_f32_16x16x32_bf16(af, bfrag[kb], acc, 0, 0, 0);
            }
            // C/D layout [measured]: col = lane&15, row e = (lane>>4)*4 + i
            float o0 = 0.f, o1 = 0.f;
            const int ebase = kgrp * 4;
            #pragma unroll
            for (int i = 0; i < 4; ++i) {
                int e = ebase + i;
                if (e < deg) {
                    int id = nbr[start + e];
                    float msg = acc[i] + b2c;
                    o0 += msg * inf0[(size_t)id*CC + cbase + col];
                    o1 += msg * inf1[(size_t)id*CC + cbase + col];
                }
            }
            // reduce over the 4 e-groups (lanes l, l^16, l^32, l^48 share col)
            o0 += __shfl_xor(o0, 16); o0 += __shfl_xor(o0, 32);
            o1 += __shfl_xor(o1, 16); o1 += __shfl_xor(o1, 32);
            if (lane < 16) {
                float invd = 1.f / (float)(deg > 0 ? deg : 1);
                out[(size_t)m*CC + cbase + lane]                   = o0 * invd;
                out[(size_t)M*CC + (size_t)m*CC + cbase + lane]    = o1 * invd;
            }
        }
        __syncthreads();  // protect hb before next node overwrites it
    }
}

extern "C" void kernel_launch(void* const* d_in, const int* in_sizes, int n_in,
                              void* d_out, int out_size, void* d_ws, size_t ws_size,
                              hipStream_t stream) {
    const float* x_in    = (const float*)d_in[0];
    const float* x_out   = (const float*)d_in[1];
    const float* in_feat = (const float*)d_in[2];
    const int*   nbr     = (const int*)d_in[3];
    const int*   rs      = (const int*)d_in[4];
    const float* W1      = (const float*)d_in[5];
    const float* b1      = (const float*)d_in[6];
    const float* W2      = (const float*)d_in[7];
    const float* b2      = (const float*)d_in[8];
    float* out = (float*)d_out;

    const int N = in_sizes[0] / 3;
    const int M = in_sizes[1] / 3;

    int grid = M < 2048 ? M : 2048;
    nmlp_kernel<<<grid, 512, 0, stream>>>(x_in, x_out, in_feat, nbr, rs,
                                          W1, b1, W2, b2, out, N, M);
}

// Round 2
// 234.518 us; speedup vs baseline: 1.4507x; 1.4507x over previous
//
#include <hip/hip_runtime.h>
#include <hip/hip_bf16.h>

#define CC 128   // channels
#define HH 128   // hidden
#define NB 8     // nodes per block iteration (DEG=16 rows each)

typedef __attribute__((ext_vector_type(8))) short frag_ab;
typedef __attribute__((ext_vector_type(4))) float f32x4;

__device__ __forceinline__ unsigned short f2bf(float f) {
    union { float f; unsigned int u; } v; v.f = f;
    unsigned int u = v.u;
    u += 0x7FFFu + ((u >> 16) & 1u);   // round-to-nearest-even
    return (unsigned short)(u >> 16);
}
__device__ __forceinline__ float bf2f(unsigned short s) {
    union { unsigned int u; float f; } v; v.u = ((unsigned int)s) << 16;
    return v.f;
}

// gelu(x) = 0.5 x (1 + erf(x/sqrt2)); erf via Abramowitz-Stegun 7.1.26
// (|err| <= 1.5e-7) -- ~15 VALU ops vs ~30 for libm erff.
__device__ __forceinline__ float gelu_f(float x) {
    float z  = fabsf(x) * 0.70710678118654752f;
    float t  = __builtin_amdgcn_rcpf(fmaf(0.3275911f, z, 1.0f));
    float p  = t * fmaf(t, fmaf(t, fmaf(t, fmaf(t, 1.061405429f, -1.453152027f),
                                        1.421413741f), -0.284496736f), 0.254829592f);
    float e  = __builtin_amdgcn_exp2f(z * z * -1.4426950408889634f);
    float er = copysignf(fmaf(-p, e, 1.0f), x);
    return 0.5f * x * (1.0f + er);
}

// fp32 -> bf16 repack of in_features into workspace (runs every call; ~60MB).
__global__ __launch_bounds__(256)
void f32_to_bf16_kernel(const float* __restrict__ in,
                        unsigned short* __restrict__ out, long n8) {
    long i = (long)blockIdx.x * blockDim.x + threadIdx.x;
    const long stride = (long)gridDim.x * blockDim.x;
    for (; i < n8; i += stride) {
        const float4* p = reinterpret_cast<const float4*>(in) + i * 2;
        float4 a = p[0], b = p[1];
        uint4 o;
        o.x = (unsigned)f2bf(a.x) | ((unsigned)f2bf(a.y) << 16);
        o.y = (unsigned)f2bf(a.z) | ((unsigned)f2bf(a.w) << 16);
        o.z = (unsigned)f2bf(b.x) | ((unsigned)f2bf(b.y) << 16);
        o.w = (unsigned)f2bf(b.z) | ((unsigned)f2bf(b.w) << 16);
        reinterpret_cast<uint4*>(out)[i] = o;
    }
}

// Block = 512 threads = 8 waves; NB=8 nodes (128 edges) per iteration.
// phase 1: h = gelu(agg@W1+b1) for 128 edges x 128 hidden -> bf16 in
//          XOR-swizzled LDS (32KB); edge neighbor ids cached in LDS.
// phase 2: per wave (16-col W2 tile): 4 MFMAs per node -> msg tile,
//          bf16 gather of in_features from ws, weighted sum, shfl-reduce
//          over the 4 e-groups, store segment mean. 8 nodes unrolled for
//          memory-level parallelism (~64 outstanding gather loads/wave).
template<bool BF16G>
__global__ __launch_bounds__(512, 4)
void nmlp_kernel(const float* __restrict__ x_in,
                 const float* __restrict__ x_out,
                 const float* __restrict__ in_feat,
                 const unsigned short* __restrict__ gws,
                 const int* __restrict__ nbr,
                 const int* __restrict__ row_splits,
                 const float* __restrict__ W1,
                 const float* __restrict__ b1,
                 const float* __restrict__ W2,
                 const float* __restrict__ b2,
                 float* __restrict__ out,
                 int N, int M)
{
    // h tile: (NB*16) rows x 256B; byte ^= (row&7)<<4 so ds_read_b128 of a
    // column strip is conflict-free (G4).
    __shared__ __align__(16) char hb[NB * 16 * 256];   // 32 KB
    __shared__ int ids_lds[NB * 16];

    const int tid  = threadIdx.x;
    const int lane = tid & 63;
    const int wave = tid >> 6;        // 0..7
    const int cbase = wave * 16;      // W2 column tile
    const int col  = lane & 15;
    const int kgrp = lane >> 4;       // 0..3

    // ---- phase-1 identity: this thread computes h[*][e0][hk0..hk0+3] ----
    const int hk0 = (tid & 31) * 4;
    const int e0  = tid >> 5;         // 0..15
    float w1v[24], b1v[4];
    #pragma unroll
    for (int kk = 0; kk < 6; ++kk)
        #pragma unroll
        for (int j = 0; j < 4; ++j)
            w1v[kk*4+j] = W1[kk*HH + hk0 + j];
    #pragma unroll
    for (int j = 0; j < 4; ++j) b1v[j] = b1[hk0 + j];
    const int wbase = e0*256 + ((hk0*2) ^ ((e0 & 7) << 4));

    // B fragments: this wave's W2 column tile (once per block)
    frag_ab bfrag[4];
    #pragma unroll
    for (int kb = 0; kb < 4; ++kb)
        #pragma unroll
        for (int i = 0; i < 8; ++i) {
            int k = kb*32 + kgrp*8 + i;
            bfrag[kb][i] = (short)f2bf(W2[k*CC + cbase + col]);
        }
    const float b2c = b2[cbase + col];
    const unsigned short* g0p = gws;
    const unsigned short* g1p = gws + (size_t)N * CC;
    const float* f0p = in_feat;
    const float* f1p = in_feat + (size_t)N * CC;

    const int rrow = lane & 15;            // A-frag row within node tile
    const int arow_off = rrow * 256;
    const int aswz = (rrow & 7) << 4;

    const int ngroups = (M + NB - 1) / NB;
    for (int g = blockIdx.x; g < ngroups; g += gridDim.x) {
        const int m0 = g * NB;

        // ---- phase 1 ----
        #pragma unroll
        for (int r = 0; r < NB; ++r) {
            const int m = m0 + r;
            const bool mvalid = (m < M);
            const int s  = mvalid ? row_splits[m] : 0;
            const int dg = mvalid ? row_splits[m+1] - s : 0;
            const bool valid = (e0 < dg);
            const int id = valid ? nbr[s + e0] : 0;
            if (hk0 == 0) ids_lds[r*16 + e0] = id;
            float a0 = valid ? x_in[id*3+0] : 0.f;
            float a1 = valid ? x_in[id*3+1] : 0.f;
            float a2 = valid ? x_in[id*3+2] : 0.f;
            float a3 = mvalid ? x_out[m*3+0] : 0.f;
            float a4 = mvalid ? x_out[m*3+1] : 0.f;
            float a5 = mvalid ? x_out[m*3+2] : 0.f;
            unsigned short us[4];
            #pragma unroll
            for (int j = 0; j < 4; ++j) {
                float pre = b1v[j];
                pre = fmaf(a0, w1v[0*4+j], pre); pre = fmaf(a1, w1v[1*4+j], pre);
                pre = fmaf(a2, w1v[2*4+j], pre); pre = fmaf(a3, w1v[3*4+j], pre);
                pre = fmaf(a4, w1v[4*4+j], pre); pre = fmaf(a5, w1v[5*4+j], pre);
                us[j] = f2bf(gelu_f(pre));
            }
            unsigned int lo = (unsigned)us[0] | ((unsigned)us[1] << 16);
            unsigned int hi = (unsigned)us[2] | ((unsigned)us[3] << 16);
            *reinterpret_cast<uint2*>(hb + r*4096 + wbase) = make_uint2(lo, hi);
        }
        __syncthreads();

        // ---- phase 2a: all MFMAs first ----
        f32x4 acc[NB];
        #pragma unroll
        for (int r = 0; r < NB; ++r) {
            f32x4 a = {0.f, 0.f, 0.f, 0.f};
            const char* base = hb + r*4096 + arow_off;
            #pragma unroll
            for (int kb = 0; kb < 4; ++kb) {
                frag_ab af = *reinterpret_cast<const frag_ab*>(
                    base + ((kb*64 + kgrp*16) ^ aswz));
                a = __builtin_amdgcn_mfma_f32_16x16x32_bf16(af, bfrag[kb], a, 0, 0, 0);
            }
            acc[r] = a;
        }

        // ---- phase 2b: gather + weighted mean (8 nodes unrolled for MLP) ----
        #pragma unroll
        for (int r = 0; r < NB; ++r) {
            const int m = m0 + r;
            if (m >= M) break;   // uniform
            const int dg = row_splits[m+1] - row_splits[m];
            const int4 ids = *reinterpret_cast<const int4*>(&ids_lds[r*16 + kgrp*4]);
            float o0 = 0.f, o1 = 0.f;
            #pragma unroll
            for (int i = 0; i < 4; ++i) {
                const int e = kgrp*4 + i;
                if (e < dg) {
                    const int id = reinterpret_cast<const int*>(&ids)[i];
                    const size_t off = (size_t)id*CC + cbase + col;
                    float gg0, gg1;
                    if (BF16G) { gg0 = bf2f(g0p[off]); gg1 = bf2f(g1p[off]); }
                    else       { gg0 = f0p[off];       gg1 = f1p[off];      }
                    const float msg = acc[r][i] + b2c;
                    o0 = fmaf(msg, gg0, o0);
                    o1 = fmaf(msg, gg1, o1);
                }
            }
            // reduce over e-groups: lanes l, l^16, l^32, l^48 share col
            o0 += __shfl_xor(o0, 16); o0 += __shfl_xor(o0, 32);
            o1 += __shfl_xor(o1, 16); o1 += __shfl_xor(o1, 32);
            if (lane < 16) {
                const float invd = 1.f / (float)(dg > 0 ? dg : 1);
                out[(size_t)m*CC + cbase + lane]                = o0 * invd;
                out[(size_t)M*CC + (size_t)m*CC + cbase + lane] = o1 * invd;
            }
        }
        __syncthreads();  // protect hb/ids before next group
    }
}

extern "C" void kernel_launch(void* const* d_in, const int* in_sizes, int n_in,
                              void* d_out, int out_size, void* d_ws, size_t ws_size,
                              hipStream_t stream) {
    const float* x_in    = (const float*)d_in[0];
    const float* x_out   = (const float*)d_in[1];
    const float* in_feat = (const float*)d_in[2];
    const int*   nbr     = (const int*)d_in[3];
    const int*   rs      = (const int*)d_in[4];
    const float* W1      = (const float*)d_in[5];
    const float* b1      = (const float*)d_in[6];
    const float* W2      = (const float*)d_in[7];
    const float* b2      = (const float*)d_in[8];
    float* out = (float*)d_out;

    const int N = in_sizes[0] / 3;
    const int M = in_sizes[1] / 3;

    const int ngroups = (M + NB - 1) / NB;
    int grid = ngroups < 2500 ? ngroups : 2500;

    const size_t nfeat = (size_t)2 * N * CC;           // B=2 per reference
    const bool use_bf16 = (ws_size >= nfeat * sizeof(unsigned short)) &&
                          (nfeat % 8 == 0);
    if (use_bf16) {
        const long n8 = (long)(nfeat / 8);
        int cgrid = (int)((n8 + 255) / 256);
        if (cgrid > 4096) cgrid = 4096;
        f32_to_bf16_kernel<<<cgrid, 256, 0, stream>>>(
            in_feat, (unsigned short*)d_ws, n8);
        nmlp_kernel<true><<<grid, 512, 0, stream>>>(
            x_in, x_out, in_feat, (const unsigned short*)d_ws,
            nbr, rs, W1, b1, W2, b2, out, N, M);
    } else {
        nmlp_kernel<false><<<grid, 512, 0, stream>>>(
            x_in, x_out, in_feat, nullptr,
            nbr, rs, W1, b1, W2, b2, out, N, M);
    }
}

// Round 3
// 115.180 us; speedup vs baseline: 2.9539x; 2.0361x over previous
//
#include <hip/hip_runtime.h>
#include <hip/hip_bf16.h>

#define CC 128   // channels
#define HH 128   // hidden
#define NB 8     // nodes per block iteration (DEG=16 rows each)

typedef __attribute__((ext_vector_type(8))) short frag_ab;
typedef __attribute__((ext_vector_type(4))) float f32x4;

__device__ __forceinline__ unsigned short f2bf(float f) {
    union { float f; unsigned int u; } v; v.f = f;
    unsigned int u = v.u;
    u += 0x7FFFu + ((u >> 16) & 1u);   // round-to-nearest-even
    return (unsigned short)(u >> 16);
}
__device__ __forceinline__ void bf2x2(unsigned int w, float& lo, float& hi) {
    union { unsigned int u; float f; } a, c;
    a.u = w << 16; c.u = w & 0xFFFF0000u;
    lo = a.f; hi = c.f;
}

// gelu via Abramowitz-Stegun 7.1.26 erf (|err| <= 1.5e-7)
__device__ __forceinline__ float gelu_f(float x) {
    float z  = fabsf(x) * 0.70710678118654752f;
    float t  = __builtin_amdgcn_rcpf(fmaf(0.3275911f, z, 1.0f));
    float p  = t * fmaf(t, fmaf(t, fmaf(t, fmaf(t, 1.061405429f, -1.453152027f),
                                        1.421413741f), -0.284496736f), 0.254829592f);
    float e  = __builtin_amdgcn_exp2f(z * z * -1.4426950408889634f);
    float er = copysignf(fmaf(-p, e, 1.0f), x);
    return 0.5f * x * (1.0f + er);
}

// fp32 -> bf16 repack of in_features into workspace.
__global__ __launch_bounds__(256)
void f32_to_bf16_kernel(const float* __restrict__ in,
                        unsigned short* __restrict__ out, long n8) {
    long i = (long)blockIdx.x * blockDim.x + threadIdx.x;
    const long stride = (long)gridDim.x * blockDim.x;
    for (; i < n8; i += stride) {
        const float4* p = reinterpret_cast<const float4*>(in) + i * 2;
        float4 a = p[0], b = p[1];
        uint4 o;
        o.x = (unsigned)f2bf(a.x) | ((unsigned)f2bf(a.y) << 16);
        o.y = (unsigned)f2bf(a.z) | ((unsigned)f2bf(a.w) << 16);
        o.z = (unsigned)f2bf(b.x) | ((unsigned)f2bf(b.y) << 16);
        o.w = (unsigned)f2bf(b.z) | ((unsigned)f2bf(b.w) << 16);
        reinterpret_cast<uint4*>(out)[i] = o;
    }
}

// Block = 512 threads = 8 waves; NB=8 nodes per group iteration.
// phase 0: threads 0-127 stage agg rows (x_in|x_out, bf16, K-pad to 8) + ids.
// prefetch: 8x dwordx4 in_features row-chunk gathers into regs (T14 split --
//           depends only on ids, lands under phases 1/2a).
// phase 1: h = gelu(agg@W1 + b1) via 1 MFMA/wave/node (K=32, zero-padded),
//          bf16 into XOR-swizzled hb.
// phase 2a: msg = h@W2 + b2 via 4 MFMA/wave/node; bf16 into swizzled msgb.
// phase 2b: lane=(b,ehalf,cchunk), wave=node: per e, 16B msg ds_read x 16B
//           gathered g from regs, 8 fp32 fma; shfl-reduce over ehalf; mean;
//           float4 stores.
template<bool BF16G>
__global__ __launch_bounds__(512, 4)
void nmlp_kernel(const float* __restrict__ x_in,
                 const float* __restrict__ x_out,
                 const float* __restrict__ in_feat,
                 const unsigned short* __restrict__ gws,
                 const int* __restrict__ nbr,
                 const int* __restrict__ row_splits,
                 const float* __restrict__ W1,
                 const float* __restrict__ b1,
                 const float* __restrict__ W2,
                 const float* __restrict__ b2,
                 float* __restrict__ out,
                 int N, int M)
{
    // byte ^= (row&7)<<4 swizzle on 16B chunks within each 256B row (G4).
    __shared__ __align__(16) char hb[NB * 16 * 256];    // 32 KB h (bf16)
    __shared__ __align__(16) char msgb[NB * 16 * 256];  // 32 KB msg (bf16)
    __shared__ __align__(16) char aggb[NB * 16 * 16];   // 2 KB agg rows (bf16 x8)
    __shared__ int ids_lds[NB * 16];

    const int tid  = threadIdx.x;
    const int lane = tid & 63;
    const int wave = tid >> 6;        // 0..7
    const int cbase = wave * 16;      // column tile (W1 and W2 N-dim)
    const int col  = lane & 15;
    const int kgrp = lane >> 4;       // 0..3
    const int hc2  = (cbase + col) * 2;

    // W1 B-frag: k = kgrp*8+i, zero-pad k>=6 (K=32 MFMA, K_real=6)
    frag_ab w1frag;
    #pragma unroll
    for (int i = 0; i < 8; ++i) {
        int k = kgrp*8 + i;
        w1frag[i] = (k < 6) ? (short)f2bf(W1[k*HH + cbase + col]) : (short)0;
    }
    const float b1c = b1[cbase + col];

    // W2 B-frags (4 x K=32)
    frag_ab bfrag[4];
    #pragma unroll
    for (int kb = 0; kb < 4; ++kb)
        #pragma unroll
        for (int i = 0; i < 8; ++i) {
            int k = kb*32 + kgrp*8 + i;
            bfrag[kb][i] = (short)f2bf(W2[k*CC + cbase + col]);
        }
    const float b2c = b2[cbase + col];

    const unsigned short* g0p = gws;
    const unsigned short* g1p = gws + (size_t)N * CC;
    const float* f0p = in_feat;
    const float* f1p = in_feat + (size_t)N * CC;

    const int arow_off = (lane & 15) * 256;   // phase-2a A-frag row
    const int aswz = (lane & 7) << 4;

    // phase-2b identity
    const int bb     = lane >> 5;         // batch 0/1
    const int ehalf  = (lane >> 4) & 1;   // edge half
    const int cchunk = lane & 15;         // 8-col chunk

    const int ngroups = (M + NB - 1) / NB;
    for (int g = blockIdx.x; g < ngroups; g += gridDim.x) {
        const int m0 = g * NB;

        // ---- phase 0: agg rows + ids ----
        if (tid < NB*16) {
            const int r = tid >> 4, e = tid & 15;
            const int m = m0 + r;
            int id = 0; int dg = 0;
            if (m < M) { int s = row_splits[m]; dg = row_splits[m+1] - s;
                         if (e < dg) id = nbr[s + e]; }
            const bool valid = (m < M) && (e < dg);
            ids_lds[tid] = id;
            float a0=0.f,a1=0.f,a2=0.f,a3=0.f,a4=0.f,a5=0.f;
            if (valid) {
                a0 = x_in[id*3+0]; a1 = x_in[id*3+1]; a2 = x_in[id*3+2];
                a3 = x_out[m*3+0]; a4 = x_out[m*3+1]; a5 = x_out[m*3+2];
            }
            uint4 pk;
            pk.x = (unsigned)f2bf(a0) | ((unsigned)f2bf(a1) << 16);
            pk.y = (unsigned)f2bf(a2) | ((unsigned)f2bf(a3) << 16);
            pk.z = (unsigned)f2bf(a4) | ((unsigned)f2bf(a5) << 16);
            pk.w = 0u;
            *reinterpret_cast<uint4*>(&aggb[tid*16]) = pk;
        }
        __syncthreads();

        // ---- prefetch gathers for this wave's node (T14 async split) ----
        uint4 gv[8];
        if (BF16G) {
            const unsigned short* gp = bb ? g1p : g0p;
            #pragma unroll
            for (int e8 = 0; e8 < 8; ++e8) {
                const int id = ids_lds[wave*16 + ehalf*8 + e8];
                gv[e8] = *reinterpret_cast<const uint4*>(
                    gp + (size_t)id*CC + cchunk*8);
            }
        }

        // ---- phase 1: h = gelu(agg@W1 + b1) via MFMA ----
        #pragma unroll
        for (int r = 0; r < NB; ++r) {
            frag_ab af;
            #pragma unroll
            for (int i = 0; i < 8; ++i) af[i] = 0;
            if (kgrp == 0)
                af = *reinterpret_cast<const frag_ab*>(&aggb[(r*16 + col)*16]);
            f32x4 pa = {0.f, 0.f, 0.f, 0.f};
            pa = __builtin_amdgcn_mfma_f32_16x16x32_bf16(af, w1frag, pa, 0, 0, 0);
            #pragma unroll
            for (int i = 0; i < 4; ++i) {
                const int e = kgrp*4 + i;
                const float hv = gelu_f(pa[i] + b1c);
                *reinterpret_cast<unsigned short*>(
                    hb + r*4096 + e*256 + (hc2 ^ ((e & 7) << 4))) = f2bf(hv);
            }
        }
        __syncthreads();

        // ---- phase 2a: msg = h@W2 + b2 via MFMA -> msgb (bf16) ----
        #pragma unroll
        for (int r = 0; r < NB; ++r) {
            f32x4 a = {0.f, 0.f, 0.f, 0.f};
            const char* base = hb + r*4096 + arow_off;
            #pragma unroll
            for (int kb = 0; kb < 4; ++kb) {
                frag_ab af = *reinterpret_cast<const frag_ab*>(
                    base + ((kb*64 + kgrp*16) ^ aswz));
                a = __builtin_amdgcn_mfma_f32_16x16x32_bf16(af, bfrag[kb], a, 0, 0, 0);
            }
            #pragma unroll
            for (int i = 0; i < 4; ++i) {
                const int e = kgrp*4 + i;
                *reinterpret_cast<unsigned short*>(
                    msgb + r*4096 + e*256 + (hc2 ^ ((e & 7) << 4))) = f2bf(a[i] + b2c);
            }
        }
        __syncthreads();

        // ---- phase 2b: weighted segment mean ----
        const int m = m0 + wave;
        if (m < M) {
            const int dg = row_splits[m+1] - row_splits[m];
            float o[8];
            #pragma unroll
            for (int j = 0; j < 8; ++j) o[j] = 0.f;
            #pragma unroll
            for (int e8 = 0; e8 < 8; ++e8) {
                const int e = ehalf*8 + e8;
                if (e < dg) {
                    const uint4 mv = *reinterpret_cast<const uint4*>(
                        msgb + wave*4096 + e*256 + ((cchunk*16) ^ ((e & 7) << 4)));
                    uint4 gvv;
                    if (BF16G) {
                        gvv = gv[e8];
                    } else {
                        const float* fp = bb ? f1p : f0p;
                        const int id = ids_lds[wave*16 + e];
                        const float4* q = reinterpret_cast<const float4*>(
                            fp + (size_t)id*CC + cchunk*8);
                        float4 qa = q[0], qb = q[1];
                        gvv.x = (unsigned)f2bf(qa.x) | ((unsigned)f2bf(qa.y) << 16);
                        gvv.y = (unsigned)f2bf(qa.z) | ((unsigned)f2bf(qa.w) << 16);
                        gvv.z = (unsigned)f2bf(qb.x) | ((unsigned)f2bf(qb.y) << 16);
                        gvv.w = (unsigned)f2bf(qb.z) | ((unsigned)f2bf(qb.w) << 16);
                    }
                    float ml, mh, gl, gh;
                    bf2x2(mv.x, ml, mh); bf2x2(gvv.x, gl, gh);
                    o[0] = fmaf(ml, gl, o[0]); o[1] = fmaf(mh, gh, o[1]);
                    bf2x2(mv.y, ml, mh); bf2x2(gvv.y, gl, gh);
                    o[2] = fmaf(ml, gl, o[2]); o[3] = fmaf(mh, gh, o[3]);
                    bf2x2(mv.z, ml, mh); bf2x2(gvv.z, gl, gh);
                    o[4] = fmaf(ml, gl, o[4]); o[5] = fmaf(mh, gh, o[5]);
                    bf2x2(mv.w, ml, mh); bf2x2(gvv.w, gl, gh);
                    o[6] = fmaf(ml, gl, o[6]); o[7] = fmaf(mh, gh, o[7]);
                }
            }
            // reduce over ehalf partner (lane ^ 16)
            #pragma unroll
            for (int j = 0; j < 8; ++j) o[j] += __shfl_xor(o[j], 16);
            if (ehalf == 0) {
                const float invd = 1.f / (float)(dg > 0 ? dg : 1);
                float* op = out + (size_t)bb*M*CC + (size_t)m*CC + cchunk*8;
                float4 v0 = {o[0]*invd, o[1]*invd, o[2]*invd, o[3]*invd};
                float4 v1 = {o[4]*invd, o[5]*invd, o[6]*invd, o[7]*invd};
                *reinterpret_cast<float4*>(op)     = v0;
                *reinterpret_cast<float4*>(op + 4) = v1;
            }
        }
        __syncthreads();  // protect LDS before next group
    }
}

extern "C" void kernel_launch(void* const* d_in, const int* in_sizes, int n_in,
                              void* d_out, int out_size, void* d_ws, size_t ws_size,
                              hipStream_t stream) {
    const float* x_in    = (const float*)d_in[0];
    const float* x_out   = (const float*)d_in[1];
    const float* in_feat = (const float*)d_in[2];
    const int*   nbr     = (const int*)d_in[3];
    const int*   rs      = (const int*)d_in[4];
    const float* W1      = (const float*)d_in[5];
    const float* b1      = (const float*)d_in[6];
    const float* W2      = (const float*)d_in[7];
    const float* b2      = (const float*)d_in[8];
    float* out = (float*)d_out;

    const int N = in_sizes[0] / 3;
    const int M = in_sizes[1] / 3;

    const int ngroups = (M + NB - 1) / NB;
    int grid = ngroups < 1024 ? ngroups : 1024;

    const size_t nfeat = (size_t)2 * N * CC;           // B=2 per reference
    const bool use_bf16 = (ws_size >= nfeat * sizeof(unsigned short)) &&
                          (nfeat % 8 == 0);
    if (use_bf16) {
        const long n8 = (long)(nfeat / 8);
        int cgrid = (int)((n8 + 255) / 256);
        if (cgrid > 4096) cgrid = 4096;
        f32_to_bf16_kernel<<<cgrid, 256, 0, stream>>>(
            in_feat, (unsigned short*)d_ws, n8);
        nmlp_kernel<true><<<grid, 512, 0, stream>>>(
            x_in, x_out, in_feat, (const unsigned short*)d_ws,
            nbr, rs, W1, b1, W2, b2, out, N, M);
    } else {
        nmlp_kernel<false><<<grid, 512, 0, stream>>>(
            x_in, x_out, in_feat, nullptr,
            nbr, rs, W1, b1, W2, b2, out, N, M);
    }
}

// Round 5
// 89.039 us; speedup vs baseline: 3.8211x; 1.2936x over previous
//
#include <hip/hip_runtime.h>
#include <hip/hip_bf16.h>

#define CC 128   // channels
#define HH 128   // hidden
#define NB 8     // nodes per block iteration (DEG=16 rows each)

typedef __attribute__((ext_vector_type(8))) _Float16 half8;
typedef __attribute__((ext_vector_type(2))) _Float16 half2v;
typedef __attribute__((ext_vector_type(2))) __fp16   fp16x2;
typedef __attribute__((ext_vector_type(4))) float f32x4;

union H2U { half2v h; fp16x2 g; unsigned int u; };

__device__ __forceinline__ unsigned int pkrtz(float a, float b) {
    H2U v; v.g = __builtin_amdgcn_cvt_pkrtz(a, b); return v.u;
}

// gelu via tanh form: 0.5x(1+tanh(0.79788456(x+0.044715x^3))), max err ~3e-4.
// 0.5(1+tanh(y)) = sigmoid(2y); gelu = x - x*sigmoid(-2y) = x*(1 - 1/(1+e^{2y}))
// 8 VALU ops (2 trans), saturates correctly for |x| large.
__device__ __forceinline__ float gelu_f(float x) {
    float x2 = x * x;
    float t  = fmaf(0.044715f, x2, 1.0f);
    float a  = x * t;
    float e  = __builtin_amdgcn_exp2f(a * 2.3022092f);
    float r  = __builtin_amdgcn_rcpf(e + 1.0f);
    return fmaf(-x, r, x);
}

// fp32 -> f16 repack of in_features into workspace (RNE via scalar casts;
// memory-bound, ops are free here).
__global__ __launch_bounds__(256)
void f32_to_f16_kernel(const float* __restrict__ in,
                       _Float16* __restrict__ out, long n8) {
    long i = (long)blockIdx.x * blockDim.x + threadIdx.x;
    const long stride = (long)gridDim.x * blockDim.x;
    for (; i < n8; i += stride) {
        const float4* p = reinterpret_cast<const float4*>(in) + i * 2;
        float4 a = p[0], b = p[1];
        half8 o;
        o[0] = (_Float16)a.x; o[1] = (_Float16)a.y;
        o[2] = (_Float16)a.z; o[3] = (_Float16)a.w;
        o[4] = (_Float16)b.x; o[5] = (_Float16)b.y;
        o[6] = (_Float16)b.z; o[7] = (_Float16)b.w;
        *reinterpret_cast<half8*>(out + i * 8) = o;
    }
}

// Block = 512 threads = 8 waves; NB=8 nodes per group iteration. All f16.
// phase 0: threads 0-127 stage agg rows (f16, K-pad to 8) + ids.
// prefetch: 8x dwordx4 f16 feature row-chunk gathers into regs (T14 split).
// phase 1: pre^T = W1^T agg^T via mfma(w1frag, aggfrag): thread holds 4
//          consecutive hidden channels for one edge -> gelu -> cvt_pkrtz
//          pair -> ONE ds_write_b64 into XOR-swizzled hb.
// phase 2a: msg^T = W2^T h^T via mfma(bfrag, hfrag): 4 consecutive msg
//          channels per thread -> packed b64 write into msgb.
// phase 2b: lane=(batch, ehalf, cchunk), wave=node: per edge one b128 msg
//          ds_read x prefetched g regs, 4x v_pk_fma_f16; shfl-reduce over
//          ehalf; unpack once; mean; float4 stores.
template<bool F16G>
__global__ __launch_bounds__(512, 4)
void nmlp_kernel(const float* __restrict__ x_in,
                 const float* __restrict__ x_out,
                 const float* __restrict__ in_feat,
                 const _Float16* __restrict__ gws,
                 const int* __restrict__ nbr,
                 const int* __restrict__ row_splits,
                 const float* __restrict__ W1,
                 const float* __restrict__ b1,
                 const float* __restrict__ W2,
                 const float* __restrict__ b2,
                 float* __restrict__ out,
                 int N, int M)
{
    // byte ^= (row&7)<<4 swizzle on 16B chunks within each 256B row (G4).
    __shared__ __align__(16) char hb[NB * 16 * 256];    // 32 KB h (f16)
    __shared__ __align__(16) char msgb[NB * 16 * 256];  // 32 KB msg (f16)
    __shared__ __align__(16) char aggb[NB * 16 * 16];   // 2 KB agg rows (f16 x8)
    __shared__ int ids_lds[NB * 16];

    const int tid  = threadIdx.x;
    const int lane = tid & 63;
    const int wave = tid >> 6;        // 0..7
    const int cbase = wave * 16;      // channel tile (W1/W2 N-dim)
    const int l15  = lane & 15;       // edge index in phases 1/2a
    const int kgrp = lane >> 4;       // 0..3

    // W1 A-frag: A[hk_local=lane&15][k=kgrp*8+i], zero-pad k>=6
    half8 w1frag;
    #pragma unroll
    for (int i = 0; i < 8; ++i) {
        int k = kgrp*8 + i;
        w1frag[i] = (k < 6) ? (_Float16)W1[k*HH + cbase + l15] : (_Float16)0.f;
    }
    // W2 A-frags: A[c_local=lane&15][k=kb*32+kgrp*8+i]
    half8 bfrag[4];
    #pragma unroll
    for (int kb = 0; kb < 4; ++kb)
        #pragma unroll
        for (int i = 0; i < 8; ++i) {
            int k = kb*32 + kgrp*8 + i;
            bfrag[kb][i] = (_Float16)W2[k*CC + cbase + l15];
        }
    // biases indexed by output-channel rows held by this thread
    float b1v[4], b2v[4];
    #pragma unroll
    for (int i = 0; i < 4; ++i) {
        b1v[i] = b1[cbase + kgrp*4 + i];
        b2v[i] = b2[cbase + kgrp*4 + i];
    }

    const _Float16* g0p = gws;
    const _Float16* g1p = gws + (size_t)N * CC;
    const float* f0p = in_feat;
    const float* f1p = in_feat + (size_t)N * CC;

    const int arow_off = l15 * 256;        // phase-2a h row (edge)
    const int aswz = (l15 & 7) << 4;
    const int wcol_off = (cbase + kgrp*4) * 2;   // packed write byte offset

    // phase-2b identity
    const int bb     = lane >> 5;          // batch 0/1
    const int ehalf  = (lane >> 4) & 1;    // edge half
    const int cchunk = lane & 15;          // 8-channel chunk

    const int ngroups = (M + NB - 1) / NB;
    for (int g = blockIdx.x; g < ngroups; g += gridDim.x) {
        const int m0 = g * NB;

        // ---- phase 0: agg rows + ids ----
        if (tid < NB*16) {
            const int r = tid >> 4, e = tid & 15;
            const int m = m0 + r;
            int id = 0; int dg = 0;
            if (m < M) { int s = row_splits[m]; dg = row_splits[m+1] - s;
                         if (e < dg) id = nbr[s + e]; }
            const bool valid = (m < M) && (e < dg);
            ids_lds[tid] = id;
            float a0=0.f,a1=0.f,a2=0.f,a3=0.f,a4=0.f,a5=0.f;
            if (valid) {
                a0 = x_in[id*3+0]; a1 = x_in[id*3+1]; a2 = x_in[id*3+2];
                a3 = x_out[m*3+0]; a4 = x_out[m*3+1]; a5 = x_out[m*3+2];
            }
            uint4 pk;
            pk.x = pkrtz(a0, a1);
            pk.y = pkrtz(a2, a3);
            pk.z = pkrtz(a4, a5);
            pk.w = 0u;
            *reinterpret_cast<uint4*>(&aggb[tid*16]) = pk;
        }
        __syncthreads();

        // ---- prefetch f16 feature gathers (T14 async split) ----
        uint4 gv[8];
        if (F16G) {
            const _Float16* gp = bb ? g1p : g0p;
            #pragma unroll
            for (int e8 = 0; e8 < 8; ++e8) {
                const int id = ids_lds[wave*16 + ehalf*8 + e8];
                gv[e8] = *reinterpret_cast<const uint4*>(
                    gp + (size_t)id*CC + cchunk*8);
            }
        }

        // ---- phase 1: pre^T = mfma(W1frag, aggfrag) -> gelu -> hb ----
        #pragma unroll
        for (int r = 0; r < NB; ++r) {
            half8 af;
            #pragma unroll
            for (int i = 0; i < 8; ++i) af[i] = (_Float16)0.f;
            if (kgrp == 0)
                af = *reinterpret_cast<const half8*>(&aggb[(r*16 + l15)*16]);
            f32x4 pa = {0.f, 0.f, 0.f, 0.f};
            pa = __builtin_amdgcn_mfma_f32_16x16x32_f16(w1frag, af, pa, 0, 0, 0);
            // pa[i] = pre[hk = cbase+kgrp*4+i][e = l15]
            float g0 = gelu_f(pa[0] + b1v[0]);
            float g1 = gelu_f(pa[1] + b1v[1]);
            float g2 = gelu_f(pa[2] + b1v[2]);
            float g3 = gelu_f(pa[3] + b1v[3]);
            uint2 w = make_uint2(pkrtz(g0, g1), pkrtz(g2, g3));
            *reinterpret_cast<uint2*>(
                hb + r*4096 + l15*256 + (wcol_off ^ aswz)) = w;
        }
        __syncthreads();

        // ---- phase 2a: msg^T = mfma(W2frag, hfrag) -> msgb ----
        #pragma unroll
        for (int r = 0; r < NB; ++r) {
            f32x4 a = {0.f, 0.f, 0.f, 0.f};
            const char* base = hb + r*4096 + arow_off;
            #pragma unroll
            for (int kb = 0; kb < 4; ++kb) {
                half8 hf = *reinterpret_cast<const half8*>(
                    base + ((kb*64 + kgrp*16) ^ aswz));
                a = __builtin_amdgcn_mfma_f32_16x16x32_f16(bfrag[kb], hf, a, 0, 0, 0);
            }
            // a[i] = msg[c = cbase+kgrp*4+i][e = l15]
            uint2 w = make_uint2(pkrtz(a[0] + b2v[0], a[1] + b2v[1]),
                                 pkrtz(a[2] + b2v[2], a[3] + b2v[3]));
            *reinterpret_cast<uint2*>(
                msgb + r*4096 + l15*256 + (wcol_off ^ aswz)) = w;
        }
        __syncthreads();

        // ---- phase 2b: weighted segment mean (packed f16 fma) ----
        const int m = m0 + wave;
        if (m < M) {
            const int dg = row_splits[m+1] - row_splits[m];
            half2v o0 = {0,0}, o1 = {0,0}, o2 = {0,0}, o3 = {0,0};
            #pragma unroll
            for (int e8 = 0; e8 < 8; ++e8) {
                const int e = ehalf*8 + e8;
                if (e < dg) {
                    const uint4 mv = *reinterpret_cast<const uint4*>(
                        msgb + wave*4096 + e*256 + ((cchunk*16) ^ ((e & 7) << 4)));
                    uint4 gvv;
                    if (F16G) {
                        gvv = gv[e8];
                    } else {
                        const float* fp = bb ? f1p : f0p;
                        const int id = ids_lds[wave*16 + e];
                        const float4* q = reinterpret_cast<const float4*>(
                            fp + (size_t)id*CC + cchunk*8);
                        float4 qa = q[0], qb = q[1];
                        gvv.x = pkrtz(qa.x, qa.y); gvv.y = pkrtz(qa.z, qa.w);
                        gvv.z = pkrtz(qb.x, qb.y); gvv.w = pkrtz(qb.z, qb.w);
                    }
                    H2U ma, ga;
                    ma.u = mv.x; ga.u = gvv.x; o0 += ma.h * ga.h;
                    ma.u = mv.y; ga.u = gvv.y; o1 += ma.h * ga.h;
                    ma.u = mv.z; ga.u = gvv.z; o2 += ma.h * ga.h;
                    ma.u = mv.w; ga.u = gvv.w; o3 += ma.h * ga.h;
                }
            }
            // reduce over ehalf partner (lane ^ 16), still packed f16
            H2U u0, u1, u2, u3, p;
            u0.h = o0; u1.h = o1; u2.h = o2; u3.h = o3;
            p.u = (unsigned int)__shfl_xor((int)u0.u, 16); u0.h += p.h;
            p.u = (unsigned int)__shfl_xor((int)u1.u, 16); u1.h += p.h;
            p.u = (unsigned int)__shfl_xor((int)u2.u, 16); u2.h += p.h;
            p.u = (unsigned int)__shfl_xor((int)u3.u, 16); u3.h += p.h;
            if (ehalf == 0) {
                const float invd = 1.f / (float)(dg > 0 ? dg : 1);
                float* op = out + (size_t)bb*M*CC + (size_t)m*CC + cchunk*8;
                float4 v0 = {(float)u0.h[0]*invd, (float)u0.h[1]*invd,
                             (float)u1.h[0]*invd, (float)u1.h[1]*invd};
                float4 v1 = {(float)u2.h[0]*invd, (float)u2.h[1]*invd,
                             (float)u3.h[0]*invd, (float)u3.h[1]*invd};
                *reinterpret_cast<float4*>(op)     = v0;
                *reinterpret_cast<float4*>(op + 4) = v1;
            }
        }
        __syncthreads();  // protect LDS before next group
    }
}

extern "C" void kernel_launch(void* const* d_in, const int* in_sizes, int n_in,
                              void* d_out, int out_size, void* d_ws, size_t ws_size,
                              hipStream_t stream) {
    const float* x_in    = (const float*)d_in[0];
    const float* x_out   = (const float*)d_in[1];
    const float* in_feat = (const float*)d_in[2];
    const int*   nbr     = (const int*)d_in[3];
    const int*   rs      = (const int*)d_in[4];
    const float* W1      = (const float*)d_in[5];
    const float* b1      = (const float*)d_in[6];
    const float* W2      = (const float*)d_in[7];
    const float* b2      = (const float*)d_in[8];
    float* out = (float*)d_out;

    const int N = in_sizes[0] / 3;
    const int M = in_sizes[1] / 3;

    const int ngroups = (M + NB - 1) / NB;
    int grid = ngroups < 1024 ? ngroups : 1024;

    const size_t nfeat = (size_t)2 * N * CC;           // B=2 per reference
    const bool use_f16 = (ws_size >= nfeat * sizeof(_Float16)) &&
                         (nfeat % 8 == 0);
    if (use_f16) {
        const long n8 = (long)(nfeat / 8);
        int cgrid = (int)((n8 + 255) / 256);
        if (cgrid > 4096) cgrid = 4096;
        f32_to_f16_kernel<<<cgrid, 256, 0, stream>>>(
            in_feat, (_Float16*)d_ws, n8);
        nmlp_kernel<true><<<grid, 512, 0, stream>>>(
            x_in, x_out, in_feat, (const _Float16*)d_ws,
            nbr, rs, W1, b1, W2, b2, out, N, M);
    } else {
        nmlp_kernel<false><<<grid, 512, 0, stream>>>(
            x_in, x_out, in_feat, nullptr,
            nbr, rs, W1, b1, W2, b2, out, N, M);
    }
}